// Round 11
// baseline (304.449 us; speedup 1.0000x reference)
//
#include <hip/hip_runtime.h>
#include <math.h>

typedef __attribute__((ext_vector_type(8))) __bf16 bf16x8;
typedef __attribute__((ext_vector_type(4))) __bf16 bf16x4;
typedef __attribute__((ext_vector_type(4))) float f32x4;

#define TSEQ 2048
#define HDIM 3584
#define NQH  16
#define NKVH 8
#define DH   256
#define WIN  1024
#define QKD  (NQH * DH)   /* 4096 */
#define KVD  (NKVH * DH)  /* 2048 */
#define QLD  8256         /* qkv row stride (8192 + 64 pad: kill pow-2) */
#define OLD  4160         /* o_bf row stride (4096 + 64) */
#define WOLD 4160         /* WoT row stride (4096 + 64) */
#define VLD  2112         /* vT row stride (2048 + 64) */

#define MFMA __builtin_amdgcn_mfma_f32_16x16x32_bf16

__device__ __forceinline__ void gload_lds16(const void* g, void* l) {
  __builtin_amdgcn_global_load_lds(
      (const __attribute__((address_space(1))) void*)g,
      (__attribute__((address_space(3))) void*)l, 16, 0, 0);
}

// ---------------- prep kernels ----------------

__global__ void cvt_bf16_kernel(const float* __restrict__ in,
                                __bf16* __restrict__ out, long n) {
  long i = ((long)blockIdx.x * blockDim.x + threadIdx.x) * 4;
  if (i >= n) return;
  float4 v = *reinterpret_cast<const float4*>(in + i);
  bf16x4 o4;
  o4.x = (__bf16)v.x; o4.y = (__bf16)v.y; o4.z = (__bf16)v.z; o4.w = (__bf16)v.w;
  *reinterpret_cast<bf16x4*>(out + i) = o4;
}

// all 4 weight transposes (fp32 RxC -> bf16 CxR, ld ldo) in one launch
__global__ void transpose_all_kernel(const float* __restrict__ Wq,
                                     const float* __restrict__ Wk,
                                     const float* __restrict__ Wv,
                                     const float* __restrict__ Wo,
                                     __bf16* __restrict__ WqT,
                                     __bf16* __restrict__ WkT,
                                     __bf16* __restrict__ WvT,
                                     __bf16* __restrict__ WoT) {
  __shared__ float tile[64][65];
  int id = blockIdx.x;
  const float* src; __bf16* dst; int R, C, ldo;
  if (id < 3584)      { src = Wq; dst = WqT; R = HDIM; C = QKD; ldo = HDIM; }
  else if (id < 5376) { id -= 3584; src = Wk; dst = WkT; R = HDIM; C = KVD; ldo = HDIM; }
  else if (id < 7168) { id -= 5376; src = Wv; dst = WvT; R = HDIM; C = KVD; ldo = HDIM; }
  else                { id -= 7168; src = Wo; dst = WoT; R = QKD; C = HDIM; ldo = WOLD; }
  const int nbx = C >> 6;
  const int c0 = (id % nbx) * 64, r0 = (id / nbx) * 64;
  const int tid = threadIdx.x;  // 256
#pragma unroll
  for (int it = 0; it < 4; ++it) {
    int f = tid + it * 256;
    int row = f >> 4, c4 = (f & 15) * 4;
    float4 v = *reinterpret_cast<const float4*>(&src[(size_t)(r0 + row) * C + c0 + c4]);
    tile[row][c4] = v.x; tile[row][c4 + 1] = v.y;
    tile[row][c4 + 2] = v.z; tile[row][c4 + 3] = v.w;
  }
  __syncthreads();
#pragma unroll
  for (int it = 0; it < 2; ++it) {
    int s = tid + it * 256;
    int oc = s >> 3, rb = (s & 7) * 8;
    bf16x8 o8;
#pragma unroll
    for (int j = 0; j < 8; ++j) o8[j] = (__bf16)tile[rb + j][oc];
    *reinterpret_cast<bf16x8*>(&dst[(size_t)(c0 + oc) * ldo + r0 + rb]) = o8;
  }
}

// in: R x C bf16 (leading dim ldin) -> out: C x R bf16 (leading dim ldout)
__global__ void transpose_bf16_kernel(const __bf16* __restrict__ in,
                                      __bf16* __restrict__ out, int ldin, int ldout) {
  __shared__ __bf16 tile[32][33];
  const int tx = threadIdx.x, ty = threadIdx.y;
  const int c0 = blockIdx.x * 32, r0 = blockIdx.y * 32;
#pragma unroll
  for (int i = 0; i < 4; ++i)
    tile[ty + i * 8][tx] = in[(size_t)(r0 + ty + i * 8) * ldin + (c0 + tx)];
  __syncthreads();
#pragma unroll
  for (int i = 0; i < 4; ++i)
    out[(size_t)(c0 + ty + i * 8) * ldout + (r0 + tx)] = tile[tx][ty + i * 8];
}

__global__ void rope_table_kernel(const int* __restrict__ positions,
                                  float* __restrict__ ct,
                                  float* __restrict__ st) {
  int i = blockIdx.x * blockDim.x + threadIdx.x;
  if (i >= TSEQ * 128) return;
  int t = i >> 7, j = i & 127;
  float invf = (float)exp((double)(-2 * j) * (9.210340371976184 / 256.0));
  float ang = (float)positions[t] * invf;
  ct[i] = cosf(ang);
  st[i] = sinf(ang);
}

// RoPE over q heads (scale 1/16) and k heads (scale 1); bf16x8-vectorized
__global__ void rope_qk_kernel(__bf16* __restrict__ qkv,
                               const float* __restrict__ ct,
                               const float* __restrict__ st) {
  int i = blockIdx.x * blockDim.x + threadIdx.x;  // TSEQ*24*16
  int jg = (i & 15) * 8;
  int th = i >> 4;
  int t = th / 24;
  int hh = th - t * 24;
  float scale = (hh < 16) ? 0.0625f : 1.0f;
  size_t base = (size_t)t * QLD + ((hh < 16) ? hh * DH : QKD + (hh - 16) * DH) + jg;
  bf16x8 x1 = *reinterpret_cast<const bf16x8*>(qkv + base);
  bf16x8 x2 = *reinterpret_cast<const bf16x8*>(qkv + base + 128);
  const float* cp = ct + (t << 7) + jg;
  const float* sp = st + (t << 7) + jg;
  bf16x8 o1, o2;
#pragma unroll
  for (int e = 0; e < 8; ++e) {
    float c = cp[e], s = sp[e];
    float a = (float)x1[e], b = (float)x2[e];
    o1[e] = (__bf16)((a * c - b * s) * scale);
    o2[e] = (__bf16)((b * c + a * s) * scale);
  }
  *reinterpret_cast<bf16x8*>(qkv + base) = o1;
  *reinterpret_cast<bf16x8*>(qkv + base + 128) = o2;
}

// split-K reduce with bf16 partials: out = fp32(p0 + p1)
__global__ void reduce2_kernel(const __bf16* __restrict__ p0,
                               const __bf16* __restrict__ p1,
                               float* __restrict__ out, int n8) {
  int stride = gridDim.x * blockDim.x;
  for (int i = blockIdx.x * blockDim.x + threadIdx.x; i < n8; i += stride) {
    bf16x8 a = reinterpret_cast<const bf16x8*>(p0)[i];
    bf16x8 b = reinterpret_cast<const bf16x8*>(p1)[i];
    float4 o0, o1;
    o0.x = (float)a[0] + (float)b[0]; o0.y = (float)a[1] + (float)b[1];
    o0.z = (float)a[2] + (float)b[2]; o0.w = (float)a[3] + (float)b[3];
    o1.x = (float)a[4] + (float)b[4]; o1.y = (float)a[5] + (float)b[5];
    o1.z = (float)a[6] + (float)b[6]; o1.w = (float)a[7] + (float)b[7];
    reinterpret_cast<float4*>(out)[2 * i] = o0;
    reinterpret_cast<float4*>(out)[2 * i + 1] = o1;
  }
}

// ---------------- 256x256 8-phase GEMM, 2 K-tiles/iter (48% util) ----------------

__device__ __forceinline__ void stage_half(const __bf16* __restrict__ gbase,
                                           int row0, int ldg, int k0,
                                           __bf16* lds_half, int tid) {
  const int lane = tid & 63;
  const int w = tid >> 6;
  const int lr = lane >> 3;                    // row&7 within half
  const int swzcol = ((lane & 7) ^ lr) << 3;   // pre-swizzled source column
  const __bf16* g = gbase + (size_t)(row0 + w * 8 + lr) * ldg + k0 + swzcol;
  __bf16* l = lds_half + w * 512;              // wave-uniform dest (elements)
  gload_lds16(g, l);
  gload_lds16(g + (size_t)64 * ldg, l + 4096);
}

#define BAR __builtin_amdgcn_s_barrier()

#define RD_A(DST, BASE, MO)                                         \
  _Pragma("unroll")                                                 \
  for (int m_ = 0; m_ < 4; ++m_) {                                  \
    const __bf16* p_ = (BASE) + (((MO) + m_) * 16 + l15) * 64;      \
    DST[m_][0] = *(const bf16x8*)(p_ + kxa);                        \
    DST[m_][1] = *(const bf16x8*)(p_ + kxb);                        \
  }

#define RD_B(DST, BASE, NO)                                         \
  _Pragma("unroll")                                                 \
  for (int n_ = 0; n_ < 2; ++n_) {                                  \
    const __bf16* p_ = (BASE) + (bro + ((NO) + n_) * 16 + l15) * 64;\
    DST[n_][0] = *(const bf16x8*)(p_ + kxa);                        \
    DST[n_][1] = *(const bf16x8*)(p_ + kxb);                        \
  }

#define MQUAD(AF, BF, MO, NO)                                          \
  __builtin_amdgcn_s_setprio(1);                                       \
  _Pragma("unroll")                                                    \
  for (int m_ = 0; m_ < 4; ++m_)                                       \
    _Pragma("unroll")                                                  \
    for (int n_ = 0; n_ < 2; ++n_) {                                   \
      acc[(MO) + m_][(NO) + n_] =                                      \
          MFMA(AF[m_][0], BF[n_][0], acc[(MO) + m_][(NO) + n_], 0, 0, 0); \
      acc[(MO) + m_][(NO) + n_] =                                      \
          MFMA(AF[m_][1], BF[n_][1], acc[(MO) + m_][(NO) + n_], 0, 0, 0); \
    }                                                                  \
  __builtin_amdgcn_s_setprio(0);

template <typename CT>
__global__ __launch_bounds__(512, 2) void gemm256_kernel(
    const __bf16* __restrict__ A, const __bf16* __restrict__ B,
    CT* __restrict__ C, int lda, int Klen, int ldc, int nrc, size_t cstride) {
  __shared__ __bf16 lds[2][2][2][8192];  // [tile-parity][A=0/B=1][half][128*64]

  const int nwg = gridDim.x;
  const int per = nwg >> 3;
  const int wg = (blockIdx.x & 7) * per + (blockIdx.x >> 3);  // XCD chunk swizzle
  const int kslice = wg / nrc;
  const int rem = wg - kslice * nrc;
  const int row0 = (rem & 7) * 256;        // col-major decode: XCD owns col-band
  const int col0 = (rem >> 3) * 256;
  const int k0 = kslice * Klen;
  CT* Cs = C + (size_t)kslice * cstride;

  const int tid = threadIdx.x;
  const int lane = tid & 63, w = tid >> 6;
  const int wr = w >> 2, wc = w & 3;
  const int l15 = lane & 15, lg = lane >> 4;
  const int swz = (lane & 7) << 3;
  const int kxa = (lg * 8) ^ swz;        // ksub 0
  const int kxb = (32 + lg * 8) ^ swz;   // ksub 1
  const int bro = (wc & 1) * 64;

  const __bf16* Ablk = A + (size_t)row0 * lda + k0;
  const __bf16* Bblk = B + (size_t)col0 * lda + k0;

  const __bf16* Ae = &lds[0][0][wr][0];
  const __bf16* Be = &lds[0][1][wc >> 1][0];
  const __bf16* Ao = &lds[1][0][wr][0];
  const __bf16* Bo = &lds[1][1][wc >> 1][0];

  f32x4 acc[8][4] = {};
  const int NT = Klen >> 6;
  const int NI = NT >> 1;

  // prologue: tile0 all halves -> buf0; tile1 A halves -> buf1
  stage_half(Ablk, 0,   lda, 0,  &lds[0][0][0][0], tid);
  stage_half(Ablk, 128, lda, 0,  &lds[0][0][1][0], tid);
  stage_half(Bblk, 0,   lda, 0,  &lds[0][1][0][0], tid);
  stage_half(Bblk, 128, lda, 0,  &lds[0][1][1][0], tid);
  stage_half(Ablk, 0,   lda, 64, &lds[1][0][0][0], tid);
  stage_half(Ablk, 128, lda, 64, &lds[1][0][1][0], tid);
  asm volatile("s_waitcnt vmcnt(4)" ::: "memory");
  BAR;

  bf16x8 a03[4][2], a47[4][2], b01[2][2], b23[2][2];

  for (int j = 0; j < NI; ++j) {
    const int e = 2 * j, o = 2 * j + 1;
    const bool last = (j == NI - 1);

    RD_A(a03, Ae, 0);
    RD_B(b01, Be, 0);
    stage_half(Bblk, 0, lda, o * 64, &lds[1][1][0][0], tid);
    asm volatile("s_waitcnt lgkmcnt(8)" ::: "memory");
    BAR; MQUAD(a03, b01, 0, 0); BAR;

    RD_A(a47, Ae, 4);
    stage_half(Bblk, 128, lda, o * 64, &lds[1][1][1][0], tid);
    BAR; MQUAD(a47, b01, 4, 0); BAR;

    RD_B(b23, Be, 2);
    if (!last) stage_half(Ablk, 0, lda, (e + 2) * 64, &lds[0][0][0][0], tid);
    BAR; MQUAD(a47, b23, 4, 2); BAR;

    if (!last) {
      stage_half(Ablk, 128, lda, (e + 2) * 64, &lds[0][0][1][0], tid);
      asm volatile("s_waitcnt vmcnt(4)" ::: "memory");
    } else {
      asm volatile("s_waitcnt vmcnt(0)" ::: "memory");
    }
    BAR; MQUAD(a03, b23, 0, 2); BAR;

    RD_A(a03, Ao, 0);
    RD_B(b01, Bo, 0);
    if (!last) stage_half(Bblk, 0, lda, (e + 2) * 64, &lds[0][1][0][0], tid);
    asm volatile("s_waitcnt lgkmcnt(8)" ::: "memory");
    BAR; MQUAD(a03, b01, 0, 0); BAR;

    RD_A(a47, Ao, 4);
    if (!last) stage_half(Bblk, 128, lda, (e + 2) * 64, &lds[0][1][1][0], tid);
    BAR; MQUAD(a47, b01, 4, 0); BAR;

    RD_B(b23, Bo, 2);
    if (!last) stage_half(Ablk, 0, lda, (o + 2) * 64, &lds[1][0][0][0], tid);
    BAR; MQUAD(a47, b23, 4, 2); BAR;

    if (!last) {
      stage_half(Ablk, 128, lda, (o + 2) * 64, &lds[1][0][1][0], tid);
      asm volatile("s_waitcnt vmcnt(4)" ::: "memory");
    }
    BAR; MQUAD(a03, b23, 0, 2); BAR;
  }

#pragma unroll
  for (int m = 0; m < 8; ++m)
#pragma unroll
    for (int n = 0; n < 4; ++n)
#pragma unroll
      for (int r = 0; r < 4; ++r) {
        int row = row0 + wr * 128 + m * 16 + lg * 4 + r;
        int col = col0 + wc * 64 + n * 16 + l15;
        Cs[(size_t)row * ldc + col] = (CT)acc[m][n][r];
      }
}

// ---------------- flash attention: 4-wave blocks, 2 blocks/CU ----------------
// grid = (8 kv-heads, 64) -> id%8 = kv-head = XCD (K/V L2-affine).
// blockIdx.y: bit0 = q-head parity, bits1+ = q-tile (reversed, LPT).
// 256 thr = 4 waves x 16 q-rows = 64 rows of ONE q-head; 2 blocks/CU.
// Fixed-max softmax (|s|<=50): p = exp(-100/(e^{.04x}+1)), no rescale.

__device__ __forceinline__ void attn_stage(const __bf16* __restrict__ kg,
                                           const __bf16* __restrict__ vg,
                                           __bf16* Kd, __bf16* Vd, int tid) {
#pragma unroll
  for (int i = 0; i < 8; ++i) {
    int c = tid + i * 256;
    int krow = c >> 5, kslot = c & 31;             // K: [64 keys][256 d]
    gload_lds16(kg + (size_t)krow * QLD + ((kslot ^ (krow & 7)) * 8), Kd + c * 8);
    int vrow = c >> 3, vslot = c & 7;              // V: [256 d][64 keys]
    gload_lds16(vg + (size_t)vrow * VLD + ((vslot ^ (vrow & 7)) * 8), Vd + c * 8);
  }
}

__global__ __launch_bounds__(256, 2) void attn_kernel(
    const __bf16* __restrict__ q, const __bf16* __restrict__ k,
    const __bf16* __restrict__ vt, __bf16* __restrict__ o) {
  __shared__ __bf16 Klds[64][256];   // [key][d], slot-swizzled
  __shared__ __bf16 Vlds[256][64];   // [d][key], slot-swizzled
  __shared__ __bf16 Plds[4][16][72]; // [wave][row][key+pad]

  const int tid = threadIdx.x;
  const int wave = tid >> 6;
  const int lane = tid & 63;
  const int l16 = lane & 15;
  const int lg = lane >> 4;
  const int h = blockIdx.x;                      // kv-head == XCD (id%8)
  const int qh = 2 * h + (blockIdx.y & 1);
  const int q0 = (31 - (int)(blockIdx.y >> 1)) << 6;  // LPT: big windows first
  const int qr = q0 + wave * 16;

  const __bf16* kg0 = k + (size_t)h * DH;
  const __bf16* vg0 = vt + (size_t)(h * DH) * VLD;

  int t_lo = q0 - (WIN - 1);
  if (t_lo < 0) t_lo = 0;
  t_lo &= ~63;
  const int NTile = ((q0 - t_lo) >> 6) + 1;

  bf16x8 qf[8];
  {
    const __bf16* qp = q + (size_t)(qr + l16) * QLD + qh * DH + lg * 8;
#pragma unroll
    for (int ds = 0; ds < 8; ++ds)
      qf[ds] = *reinterpret_cast<const bf16x8*>(qp + ds * 32);
  }

  f32x4 accO[16] = {};
  float l_run[4] = {0.f, 0.f, 0.f, 0.f};

  for (int it = 0; it < NTile; ++it) {
    const int t0 = t_lo + it * 64;

    attn_stage(kg0 + (size_t)t0 * QLD, vg0 + t0, &Klds[0][0], &Vlds[0][0], tid);
    asm volatile("s_waitcnt vmcnt(0)" ::: "memory");
    __builtin_amdgcn_s_barrier();

    // QK^T
    f32x4 accS[4] = {};
    __builtin_amdgcn_s_setprio(1);
#pragma unroll
    for (int ds = 0; ds < 8; ++ds)
#pragma unroll
      for (int nt = 0; nt < 4; ++nt) {
        int row = nt * 16 + l16;
        int slot = (4 * ds + lg) ^ (l16 & 7);
        bf16x8 kf = *reinterpret_cast<const bf16x8*>(&Klds[0][0] + row * 256 + slot * 8);
        accS[nt] = MFMA(qf[ds], kf, accS[nt], 0, 0, 0);
      }
    __builtin_amdgcn_s_setprio(0);

    // softcap+exp fixed-max, mask, P -> LDS, row-sum
    float rs[4] = {0.f, 0.f, 0.f, 0.f};
#pragma unroll
    for (int nt = 0; nt < 4; ++nt) {
      int key = t0 + nt * 16 + l16;
#pragma unroll
      for (int r = 0; r < 4; ++r) {
        int row = qr + lg * 4 + r;
        float t = __expf(accS[nt][r] * 0.04f);
        float p = __expf(-100.0f / (t + 1.0f));
        bool valid = (key <= row) && (row - key < WIN);
        p = valid ? p : 0.f;
        rs[r] += p;
        Plds[wave][lg * 4 + r][nt * 16 + l16] = (__bf16)p;
      }
    }
#pragma unroll
    for (int off = 1; off < 16; off <<= 1)
#pragma unroll
      for (int r = 0; r < 4; ++r)
        rs[r] += __shfl_xor(rs[r], off);
#pragma unroll
    for (int r = 0; r < 4; ++r)
      l_run[r] += rs[r];

    // PV
    __builtin_amdgcn_s_setprio(1);
#pragma unroll
    for (int ks = 0; ks < 2; ++ks) {
      bf16x8 pa = *reinterpret_cast<const bf16x8*>(&Plds[wave][l16][ks * 32 + lg * 8]);
#pragma unroll
      for (int nt2 = 0; nt2 < 16; ++nt2) {
        int row = nt2 * 16 + l16;
        int slot = (4 * ks + lg) ^ (l16 & 7);
        bf16x8 vb = *reinterpret_cast<const bf16x8*>(&Vlds[0][0] + row * 64 + slot * 8);
        accO[nt2] = MFMA(pa, vb, accO[nt2], 0, 0, 0);
      }
    }
    __builtin_amdgcn_s_setprio(0);
    __builtin_amdgcn_s_barrier();  // all reads done before next tile's DMA
  }

#pragma unroll
  for (int r = 0; r < 4; ++r) {
    float inv_l = 1.f / l_run[r];
    int row = qr + lg * 4 + r;
#pragma unroll
    for (int nt2 = 0; nt2 < 16; ++nt2)
      o[(size_t)row * OLD + qh * DH + nt2 * 16 + l16] = (__bf16)(accO[nt2][r] * inv_l);
  }
}

// ---------------- launcher ----------------

extern "C" void kernel_launch(void* const* d_in, const int* in_sizes, int n_in,
                              void* d_out, int out_size, void* d_ws, size_t ws_size,
                              hipStream_t stream) {
  const float* hs = (const float*)d_in[0];
  const float* Wq = (const float*)d_in[1];
  const float* Wk = (const float*)d_in[2];
  const float* Wv = (const float*)d_in[3];
  const float* Wo = (const float*)d_in[4];
  const int* positions = (const int*)d_in[5];
  float* out = (float*)d_out;

  char* ws = (char*)d_ws;
  const size_t SZ_HS  = (size_t)TSEQ * HDIM * 2;
  const size_t SZ_WQT = (size_t)QKD * HDIM * 2;
  const size_t SZ_WKT = (size_t)KVD * HDIM * 2;
  const size_t SZ_WOT = (size_t)HDIM * WOLD * 2;
  const size_t SZ_QKV = (size_t)TSEQ * QLD * 2;
  const size_t SZ_O   = (size_t)TSEQ * OLD * 2;
  const size_t SZ_TBL = (size_t)TSEQ * 128 * 4;

  __bf16* hs_bf = (__bf16*)ws; ws += SZ_HS;
  __bf16* WqT   = (__bf16*)ws; ws += SZ_WQT;   // WqT/WkT/WvT contiguous -> fused B
  __bf16* WkT   = (__bf16*)ws; ws += SZ_WKT;
  __bf16* WvT   = (__bf16*)ws; ws += SZ_WKT;
  __bf16* WoT   = (__bf16*)ws; ws += SZ_WOT;
  __bf16* qkv   = (__bf16*)ws; ws += SZ_QKV;
  __bf16* o_bf  = (__bf16*)ws; ws += SZ_O;
  float*  cost  = (float*)ws;  ws += SZ_TBL;
  float*  sint  = (float*)ws;  ws += SZ_TBL;
  __bf16* vt_bf = hs_bf;            // overlay: hs_bf dead after QKV GEMM
                                    // (vT = 2048 x VLD = 8.7MB <= 14.7MB)
  __bf16* cpart = WqT;              // overlay: weights dead after QKV GEMM;
                                    // bf16 partials 2 x 2048x3584 = 29.4MB
  if ((size_t)(ws - (char*)d_ws) > ws_size) return;

  // prep
  cvt_bf16_kernel<<<(TSEQ * HDIM) / 1024, 256, 0, stream>>>(hs, hs_bf, (long)TSEQ * HDIM);
  transpose_all_kernel<<<10752, 256, 0, stream>>>(Wq, Wk, Wv, Wo, WqT, WkT, WvT, WoT);
  rope_table_kernel<<<(TSEQ * 128) / 256, 256, 0, stream>>>(positions, cost, sint);

  // fused QKV projection: M=2048, N=8192, K=3584 -> 256 blocks (1/CU)
  gemm256_kernel<__bf16><<<256, 512, 0, stream>>>(hs_bf, WqT, qkv, HDIM, HDIM, QLD, 256, 0);

  // RoPE q+k merged (vectorized); V transpose (into hs_bf overlay)
  rope_qk_kernel<<<(TSEQ * 24 * 16) / 256, 256, 0, stream>>>(qkv, cost, sint);
  transpose_bf16_kernel<<<dim3(KVD / 32, TSEQ / 32), dim3(32, 8), 0, stream>>>(qkv + QKD + KVD, vt_bf, QLD, VLD);

  // attention: 512 blocks, 2/CU; grid.x = kv-head = XCD
  attn_kernel<<<dim3(NKVH, 64), 256, 0, stream>>>(qkv, qkv + QKD, vt_bf, o_bf);

  // output projection: split-K=2, bf16 partials -> 224 blocks, then reduce
  gemm256_kernel<__bf16><<<224, 512, 0, stream>>>(o_bf, WoT, cpart, OLD, QKD / 2, HDIM, 112,
                                                  (size_t)TSEQ * HDIM);
  reduce2_kernel<<<2048, 256, 0, stream>>>(cpart, cpart + (size_t)TSEQ * HDIM, out,
                                           TSEQ * HDIM / 8);
}